// Round 2
// baseline (485.595 us; speedup 1.0000x reference)
//
#include <hip/hip_runtime.h>
#include <stdint.h>

#define LOG2E 1.4426950408889634f

typedef __attribute__((ext_vector_type(8))) short short8;
typedef __attribute__((ext_vector_type(4))) float floatx4;

__device__ __forceinline__ float bf2f(unsigned short h) {
  union { unsigned int u; float f; } v; v.u = ((unsigned int)h) << 16; return v.f;
}
__device__ __forceinline__ unsigned short f2bf(float f) {
  union { float f; unsigned int u; } v; v.f = f;
  unsigned int r = v.u + 0x7FFFu + ((v.u >> 16) & 1u);
  return (unsigned short)(r >> 16);
}

// ---------------------------------------------------------------------------
// fp32 -> bf16 elementwise convert (8 elems/thread, vectorized)
__global__ __launch_bounds__(256) void cvt_f32_bf16(const float* __restrict__ src,
                                                    unsigned short* __restrict__ dst, int n) {
  int i = (blockIdx.x * 256 + threadIdx.x) * 8;
  if (i >= n) return;
  float4 a = ((const float4*)(src + i))[0];
  float4 b = ((const float4*)(src + i))[1];
  union { uint4 v; unsigned short u[8]; } o;
  o.u[0] = f2bf(a.x); o.u[1] = f2bf(a.y); o.u[2] = f2bf(a.z); o.u[3] = f2bf(a.w);
  o.u[4] = f2bf(b.x); o.u[5] = f2bf(b.y); o.u[6] = f2bf(b.z); o.u[7] = f2bf(b.w);
  *(uint4*)(dst + i) = o.v;
}

// ---------------------------------------------------------------------------
// Tiled transpose + fp32->bf16: src fp32 (R x C) -> dst bf16 (C x R). 64x64 tiles.
__global__ __launch_bounds__(256) void transpose_cvt(const float* __restrict__ src,
                                                     unsigned short* __restrict__ dst,
                                                     int R, int C) {
  __shared__ unsigned short tile[64][65];
  int tc = C >> 6;
  int br = blockIdx.x / tc, bc = blockIdx.x % tc;
  int r0 = br << 6, c0 = bc << 6;
  int i = threadIdx.x >> 2, cc = (threadIdx.x & 3) << 4;
  const float4* g = (const float4*)(src + (size_t)(r0 + i) * C + c0 + cc);
  float4 f0 = g[0], f1 = g[1], f2 = g[2], f3 = g[3];
  const float* fp = (const float*)&f0;  // f0..f3 contiguous? not guaranteed; do explicit
  unsigned short u[16];
  u[0]=f2bf(f0.x); u[1]=f2bf(f0.y); u[2]=f2bf(f0.z); u[3]=f2bf(f0.w);
  u[4]=f2bf(f1.x); u[5]=f2bf(f1.y); u[6]=f2bf(f1.z); u[7]=f2bf(f1.w);
  u[8]=f2bf(f2.x); u[9]=f2bf(f2.y); u[10]=f2bf(f2.z); u[11]=f2bf(f2.w);
  u[12]=f2bf(f3.x); u[13]=f2bf(f3.y); u[14]=f2bf(f3.z); u[15]=f2bf(f3.w);
  (void)fp;
#pragma unroll
  for (int j = 0; j < 16; ++j) tile[i][cc + j] = u[j];
  __syncthreads();
  union { uint4 v[2]; unsigned short u[16]; } buf;
#pragma unroll
  for (int j = 0; j < 16; ++j) buf.u[j] = tile[cc + j][i];
  uint4* o = (uint4*)(dst + (size_t)(c0 + i) * R + r0 + cc);
  o[0] = buf.v[0]; o[1] = buf.v[1];
}

// ---------------------------------------------------------------------------
// NT GEMM: C(M,N) = A(M,K) * BT(N,K)^T, bf16 in, fp32 accum, OutT out.
// 128x128 tile / block (4 waves, each 64x64 = 4x4 MFMA tiles), BK=32.
template <typename OutT>
__global__ __launch_bounds__(256) void gemm_nt(const unsigned short* __restrict__ A,
                                               const unsigned short* __restrict__ BT,
                                               OutT* __restrict__ C,
                                               int M, int N, int K) {
  __shared__ unsigned short As[128 * 40];  // pitch 40 (80B): 16B-aligned rows
  __shared__ unsigned short Bs[128 * 40];
  const int nb = N >> 7;
  const int bm = blockIdx.x / nb, bn = blockIdx.x % nb;
  const int m0 = bm << 7, n0 = bn << 7;
  const int tid = threadIdx.x;
  const int lane = tid & 63, wave = tid >> 6;
  const int l15 = lane & 15, quad = lane >> 4;
  const int wm = (wave >> 1) << 6, wn = (wave & 1) << 6;
  const int srow = tid >> 1, scol = (tid & 1) << 4;

  floatx4 acc[4][4];
#pragma unroll
  for (int i = 0; i < 4; ++i)
#pragma unroll
    for (int j = 0; j < 4; ++j) acc[i][j] = (floatx4){0.f, 0.f, 0.f, 0.f};

  const unsigned short* ag = A + (size_t)(m0 + srow) * K + scol;
  const unsigned short* bg = BT + (size_t)(n0 + srow) * K + scol;
  uint4* asw = (uint4*)(&As[srow * 40 + scol]);
  uint4* bsw = (uint4*)(&Bs[srow * 40 + scol]);

  for (int k0 = 0; k0 < K; k0 += 32) {
    uint4 a0 = ((const uint4*)(ag + k0))[0];
    uint4 a1 = ((const uint4*)(ag + k0))[1];
    uint4 b0 = ((const uint4*)(bg + k0))[0];
    uint4 b1 = ((const uint4*)(bg + k0))[1];
    __syncthreads();
    asw[0] = a0; asw[1] = a1;
    bsw[0] = b0; bsw[1] = b1;
    __syncthreads();
    short8 af[4], bf[4];
#pragma unroll
    for (int mt = 0; mt < 4; ++mt)
      af[mt] = *(const short8*)(&As[(wm + mt * 16 + l15) * 40 + quad * 8]);
#pragma unroll
    for (int nt = 0; nt < 4; ++nt)
      bf[nt] = *(const short8*)(&Bs[(wn + nt * 16 + l15) * 40 + quad * 8]);
#pragma unroll
    for (int mt = 0; mt < 4; ++mt)
#pragma unroll
      for (int nt = 0; nt < 4; ++nt)
        acc[mt][nt] = __builtin_amdgcn_mfma_f32_16x16x32_bf16(af[mt], bf[nt], acc[mt][nt], 0, 0, 0);
  }
#pragma unroll
  for (int mt = 0; mt < 4; ++mt)
#pragma unroll
    for (int nt = 0; nt < 4; ++nt)
#pragma unroll
      for (int r = 0; r < 4; ++r) {
        int m = m0 + wm + mt * 16 + quad * 4 + r;
        int n = n0 + wn + nt * 16 + l15;
        float v = acc[mt][nt][r];
        if constexpr (sizeof(OutT) == 2)
          C[(size_t)m * N + n] = (OutT)f2bf(v);
        else
          C[(size_t)m * N + n] = (OutT)v;
      }
}

// ---------------------------------------------------------------------------
// RMS-norm + RoPE for q (heads 0..15, 1/sqrt(128) folded) and k (kv 0..3).
// One wave per (b,s,head-slot) row of 128. qkv bf16; norm weights fp32.
// Writes q as (B,H,S,128) bf16, k as (B,KV,S,128) bf16.
__global__ __launch_bounds__(256) void norm_rope(const unsigned short* __restrict__ qkv,
                                                 const float* __restrict__ qw,
                                                 const float* __restrict__ kw,
                                                 unsigned short* __restrict__ qT,
                                                 unsigned short* __restrict__ kT) {
  const int S = 2048;
  int wid = blockIdx.x * 4 + (threadIdx.x >> 6);
  int lane = threadIdx.x & 63;
  int slot = wid % 20;
  int bs = wid / 20;
  int s = bs & (S - 1), b = bs >> 11;
  const unsigned short* src;
  unsigned short* dst;
  const float* w;
  float scale;
  if (slot < 16) {
    src = qkv + (size_t)bs * 3072 + slot * 128;
    dst = qT + ((size_t)(b * 16 + slot) * S + s) * 128;
    w = qw; scale = 0.08838834764831845f;  // 1/sqrt(128)
  } else {
    int kvi = slot - 16;
    src = qkv + (size_t)bs * 3072 + 2048 + kvi * 128;
    dst = kT + ((size_t)(b * 4 + kvi) * S + s) * 128;
    w = kw; scale = 1.0f;
  }
  float x1 = bf2f(src[lane]), x2 = bf2f(src[lane + 64]);
  float ss = x1 * x1 + x2 * x2;
#pragma unroll
  for (int m = 1; m < 64; m <<= 1) ss += __shfl_xor(ss, m, 64);
  float rms = rsqrtf(ss * (1.0f / 128.0f) + 1e-6f);
  float y1 = x1 * rms * w[lane];
  float y2 = x2 * rms * w[lane + 64];
  // inv_freq[lane] = 10000^(-lane/64) = 2^(-lane*log2(10000)/64)
  float ang = (float)s * exp2f((float)lane * -0.2076205059304601f);
  float c = cosf(ang), sn = sinf(ang);
  float o1 = (y1 * c - y2 * sn) * scale;
  float o2 = (y2 * c + y1 * sn) * scale;
  dst[lane] = f2bf(o1);
  dst[lane + 64] = f2bf(o2);
}

// ---------------------------------------------------------------------------
// V transpose: qkv v-slice (B,S,KV,128) bf16 -> vT (B,KV,128,S) bf16. 64x64 tiles.
__global__ __launch_bounds__(256) void v_transpose(const unsigned short* __restrict__ qkv,
                                                   unsigned short* __restrict__ vT) {
  const int S = 2048;
  int bid = blockIdx.x;
  int dt = bid & 1, st = (bid >> 1) & 31, kv = (bid >> 6) & 3, b = bid >> 8;
  int s0 = st << 6, d0 = dt << 6;
  __shared__ unsigned short tile[64][65];
  int i = threadIdx.x >> 2, cc = (threadIdx.x & 3) << 4;
  union { uint4 v[2]; unsigned short u[16]; } buf;
  const uint4* g = (const uint4*)(qkv + ((size_t)(b * S) + s0 + i) * 3072 + 2560 + kv * 128 + d0 + cc);
  buf.v[0] = g[0]; buf.v[1] = g[1];
#pragma unroll
  for (int j = 0; j < 16; ++j) tile[i][cc + j] = buf.u[j];
  __syncthreads();
#pragma unroll
  for (int j = 0; j < 16; ++j) buf.u[j] = tile[cc + j][i];
  uint4* o = (uint4*)(vT + ((size_t)(b * 4 + kv) * 128 + d0 + i) * S + s0 + cc);
  o[0] = buf.v[0]; o[1] = buf.v[1];
}

// ---------------------------------------------------------------------------
// MFMA flash attention, non-causal. Block = (b,h,64 q-rows), 4 waves (16 rows each).
// K/V tiles of 64 keys. q pre-scaled. Output ao (B,S,H,128) bf16.
__global__ __launch_bounds__(256) void flash_attn(const unsigned short* __restrict__ qT,
                                                  const unsigned short* __restrict__ kT,
                                                  const unsigned short* __restrict__ vT,
                                                  unsigned short* __restrict__ ao) {
  const int S = 2048;
  int bid = blockIdx.x;
  int qt = bid & 31, h = (bid >> 5) & 15, b = bid >> 9;
  int kv = h >> 2;
  int tid = threadIdx.x;
  int lane = tid & 63, wave = tid >> 6;
  int l15 = lane & 15, quad = lane >> 4;

  __shared__ unsigned short Qs[64 * 136];   // pitch 136 (272B)
  __shared__ unsigned short Ks[64 * 136];
  __shared__ unsigned short VTs[128 * 72];  // V^T tile: [d][key], pitch 72 (144B)
  __shared__ unsigned short Ps[4][16 * 72]; // per-wave P (C/D -> A layout round-trip)

  {
    int row = tid >> 2, cc = (tid & 3) << 5;
    const uint4* src = (const uint4*)(qT + ((size_t)(b * 16 + h) * S + qt * 64 + row) * 128 + cc);
    uint4* dst = (uint4*)(&Qs[row * 136 + cc]);
    dst[0] = src[0]; dst[1] = src[1]; dst[2] = src[2]; dst[3] = src[3];
  }
  __syncthreads();
  short8 aq[4];
#pragma unroll
  for (int kk = 0; kk < 4; ++kk)
    aq[kk] = *(const short8*)(&Qs[(wave * 16 + l15) * 136 + kk * 32 + quad * 8]);

  floatx4 O[8];
#pragma unroll
  for (int dt = 0; dt < 8; ++dt) O[dt] = (floatx4){0.f, 0.f, 0.f, 0.f};
  float m_i[4] = {-1e30f, -1e30f, -1e30f, -1e30f};
  float l_i[4] = {0.f, 0.f, 0.f, 0.f};

  const size_t kbase = (size_t)(b * 4 + kv) * S * 128;
  const size_t vbase = (size_t)(b * 4 + kv) * 128 * S;

  for (int kt = 0; kt < 32; ++kt) {
    __syncthreads();
    {
      int row = tid >> 2, cc = (tid & 3) << 5;
      const uint4* src = (const uint4*)(kT + kbase + (size_t)(kt * 64 + row) * 128 + cc);
      uint4* dst = (uint4*)(&Ks[row * 136 + cc]);
      dst[0] = src[0]; dst[1] = src[1]; dst[2] = src[2]; dst[3] = src[3];
    }
    {
      int d = tid >> 1, cc = (tid & 1) << 5;
      const uint4* src = (const uint4*)(vT + vbase + (size_t)d * S + kt * 64 + cc);
      uint4* dst = (uint4*)(&VTs[d * 72 + cc]);
      dst[0] = src[0]; dst[1] = src[1]; dst[2] = src[2]; dst[3] = src[3];
    }
    __syncthreads();

    floatx4 sa[4];
#pragma unroll
    for (int nt = 0; nt < 4; ++nt) {
      sa[nt] = (floatx4){0.f, 0.f, 0.f, 0.f};
#pragma unroll
      for (int kk = 0; kk < 4; ++kk) {
        short8 bk = *(const short8*)(&Ks[(nt * 16 + l15) * 136 + kk * 32 + quad * 8]);
        sa[nt] = __builtin_amdgcn_mfma_f32_16x16x32_bf16(aq[kk], bk, sa[nt], 0, 0, 0);
      }
    }
    // online softmax (row = quad*4+r, cols = nt*16+l15)
    float alpha[4];
#pragma unroll
    for (int r = 0; r < 4; ++r) {
      float mx = fmaxf(fmaxf(sa[0][r], sa[1][r]), fmaxf(sa[2][r], sa[3][r]));
#pragma unroll
      for (int m = 1; m < 16; m <<= 1) mx = fmaxf(mx, __shfl_xor(mx, m, 64));
      float mn = fmaxf(m_i[r], mx);
      alpha[r] = exp2f((m_i[r] - mn) * LOG2E);
      m_i[r] = mn;
    }
#pragma unroll
    for (int nt = 0; nt < 4; ++nt)
#pragma unroll
      for (int r = 0; r < 4; ++r)
        sa[nt][r] = exp2f((sa[nt][r] - m_i[r]) * LOG2E);
#pragma unroll
    for (int r = 0; r < 4; ++r) {
      float sum = sa[0][r] + sa[1][r] + sa[2][r] + sa[3][r];
#pragma unroll
      for (int m = 1; m < 16; m <<= 1) sum += __shfl_xor(sum, m, 64);
      l_i[r] = l_i[r] * alpha[r] + sum;
    }
#pragma unroll
    for (int dt = 0; dt < 8; ++dt)
#pragma unroll
      for (int r = 0; r < 4; ++r) O[dt][r] *= alpha[r];
    // P: C/D layout -> LDS -> A layout
#pragma unroll
    for (int nt = 0; nt < 4; ++nt)
#pragma unroll
      for (int r = 0; r < 4; ++r)
        Ps[wave][(quad * 4 + r) * 72 + nt * 16 + l15] = f2bf(sa[nt][r]);
    __syncthreads();
#pragma unroll
    for (int kk2 = 0; kk2 < 2; ++kk2) {
      short8 ap = *(const short8*)(&Ps[wave][l15 * 72 + kk2 * 32 + quad * 8]);
#pragma unroll
      for (int dt = 0; dt < 8; ++dt) {
        short8 bv = *(const short8*)(&VTs[(dt * 16 + l15) * 72 + kk2 * 32 + quad * 8]);
        O[dt] = __builtin_amdgcn_mfma_f32_16x16x32_bf16(ap, bv, O[dt], 0, 0, 0);
      }
    }
  }
#pragma unroll
  for (int r = 0; r < 4; ++r) {
    float inv = 1.0f / l_i[r];
    int s = qt * 64 + wave * 16 + quad * 4 + r;
#pragma unroll
    for (int dt = 0; dt < 8; ++dt) {
      int d = dt * 16 + l15;
      ao[((size_t)(b * S + s) * 16 + h) * 128 + d] = f2bf(O[dt][r] * inv);
    }
  }
}

// ---------------------------------------------------------------------------
extern "C" void kernel_launch(void* const* d_in, const int* in_sizes, int n_in,
                              void* d_out, int out_size, void* d_ws, size_t ws_size,
                              hipStream_t stream) {
  const float* x  = (const float*)d_in[0];
  const float* Wq = (const float*)d_in[1];
  const float* Wk = (const float*)d_in[2];
  const float* Wv = (const float*)d_in[3];
  const float* Wo = (const float*)d_in[4];
  const float* qw = (const float*)d_in[5];
  const float* kw = (const float*)d_in[6];
  float* out = (float*)d_out;

  unsigned short* p = (unsigned short*)d_ws;
  unsigned short* xbf   = p; p += (size_t)4096 * 2048;
  unsigned short* WTqkv = p; p += (size_t)3072 * 2048;
  unsigned short* WoT   = p; p += (size_t)2048 * 2048;
  unsigned short* qkv   = p; p += (size_t)4096 * 3072;
  unsigned short* qTb   = p; p += (size_t)2 * 16 * 2048 * 128;
  unsigned short* kTb   = p; p += (size_t)2 * 4 * 2048 * 128;
  unsigned short* vTb   = p; p += (size_t)2 * 4 * 2048 * 128;
  unsigned short* ao    = p; p += (size_t)4096 * 2048;

  // fp32 -> bf16: x; weights transposed+converted (NT layout for GEMMs).
  cvt_f32_bf16<<<4096, 256, 0, stream>>>(x, xbf, 4096 * 2048);
  transpose_cvt<<<1024, 256, 0, stream>>>(Wq, WTqkv, 2048, 2048);
  transpose_cvt<<<256, 256, 0, stream>>>(Wk, WTqkv + (size_t)2048 * 2048, 2048, 512);
  transpose_cvt<<<256, 256, 0, stream>>>(Wv, WTqkv + (size_t)2048 * 2048 + (size_t)512 * 2048, 2048, 512);
  transpose_cvt<<<1024, 256, 0, stream>>>(Wo, WoT, 2048, 2048);

  // Fused QKV projection: (4096 x 2048) @ (2048 x 3072), bf16 out
  gemm_nt<unsigned short><<<768, 256, 0, stream>>>(xbf, WTqkv, qkv, 4096, 3072, 2048);

  // RMS-norm + RoPE (+ scale folded into q), transposed layouts for attention
  norm_rope<<<20480, 256, 0, stream>>>(qkv, qw, kw, qTb, kTb);
  v_transpose<<<512, 256, 0, stream>>>(qkv, vTb);

  // Flash attention -> (B,S,H,128) bf16
  flash_attn<<<1024, 256, 0, stream>>>(qTb, kTb, vTb, ao);

  // Output projection, fp32 out
  gemm_nt<float><<<512, 256, 0, stream>>>(ao, WoT, out, 4096, 2048, 2048);
}

// Round 3
// 384.875 us; speedup vs baseline: 1.2617x; 1.2617x over previous
//
#include <hip/hip_runtime.h>
#include <stdint.h>

#define LOG2E 1.4426950408889634f

typedef __attribute__((ext_vector_type(8))) short short8;
typedef __attribute__((ext_vector_type(4))) float floatx4;
typedef __attribute__((ext_vector_type(4))) unsigned short ushort4v;
typedef unsigned int u32;

__device__ __forceinline__ float bf2f(unsigned short h) {
  union { unsigned int u; float f; } v; v.u = ((unsigned int)h) << 16; return v.f;
}
__device__ __forceinline__ unsigned short f2bf(float f) {
  union { float f; unsigned int u; } v; v.f = f;
  unsigned int r = v.u + 0x7FFFu + ((v.u >> 16) & 1u);
  return (unsigned short)(r >> 16);
}
// async global->LDS, 16B per lane. dst must be wave-contiguous (base + lane*16).
__device__ __forceinline__ void async16(void* lds, const void* g) {
  __builtin_amdgcn_global_load_lds((const __attribute__((address_space(1))) u32*)g,
                                   (__attribute__((address_space(3))) u32*)lds, 16, 0, 0);
}

// ---------------------------------------------------------------------------
// fp32 -> bf16 elementwise convert (8 elems/thread, vectorized)
__global__ __launch_bounds__(256) void cvt_f32_bf16(const float* __restrict__ src,
                                                    unsigned short* __restrict__ dst, int n) {
  int i = (blockIdx.x * 256 + threadIdx.x) * 8;
  if (i >= n) return;
  float4 a = ((const float4*)(src + i))[0];
  float4 b = ((const float4*)(src + i))[1];
  union { uint4 v; unsigned short u[8]; } o;
  o.u[0] = f2bf(a.x); o.u[1] = f2bf(a.y); o.u[2] = f2bf(a.z); o.u[3] = f2bf(a.w);
  o.u[4] = f2bf(b.x); o.u[5] = f2bf(b.y); o.u[6] = f2bf(b.z); o.u[7] = f2bf(b.w);
  *(uint4*)(dst + i) = o.v;
}

// ---------------------------------------------------------------------------
// Tiled transpose + fp32->bf16: src fp32 (R x C) -> dst bf16 (C x R). 64x64 tiles.
__global__ __launch_bounds__(256) void transpose_cvt(const float* __restrict__ src,
                                                     unsigned short* __restrict__ dst,
                                                     int R, int C) {
  __shared__ unsigned short tile[64][65];
  int tc = C >> 6;
  int br = blockIdx.x / tc, bc = blockIdx.x % tc;
  int r0 = br << 6, c0 = bc << 6;
  int i = threadIdx.x >> 2, cc = (threadIdx.x & 3) << 4;
  const float4* g = (const float4*)(src + (size_t)(r0 + i) * C + c0 + cc);
  float4 f0 = g[0], f1 = g[1], f2 = g[2], f3 = g[3];
  unsigned short u[16];
  u[0]=f2bf(f0.x); u[1]=f2bf(f0.y); u[2]=f2bf(f0.z); u[3]=f2bf(f0.w);
  u[4]=f2bf(f1.x); u[5]=f2bf(f1.y); u[6]=f2bf(f1.z); u[7]=f2bf(f1.w);
  u[8]=f2bf(f2.x); u[9]=f2bf(f2.y); u[10]=f2bf(f2.z); u[11]=f2bf(f2.w);
  u[12]=f2bf(f3.x); u[13]=f2bf(f3.y); u[14]=f2bf(f3.z); u[15]=f2bf(f3.w);
#pragma unroll
  for (int j = 0; j < 16; ++j) tile[i][cc + j] = u[j];
  __syncthreads();
  union { uint4 v[2]; unsigned short u[16]; } buf;
#pragma unroll
  for (int j = 0; j < 16; ++j) buf.u[j] = tile[cc + j][i];
  uint4* o = (uint4*)(dst + (size_t)(c0 + i) * R + r0 + cc);
  o[0] = buf.v[0]; o[1] = buf.v[1];
}

// ---------------------------------------------------------------------------
// NT GEMM: C(M,N) = A(M,K) * BT(N,K)^T, bf16 in, fp32 accum, OutT out.
// 128x128 tile, BK=32, global_load_lds(16B) staging with 2-bit XOR swizzle.
// LDS slot for (row, chunk c of 4): row*4 + (c ^ ((row>>1)&3)) -> 2-way banks (free).
template <typename OutT>
__global__ __launch_bounds__(256) void gemm_nt(const unsigned short* __restrict__ A,
                                               const unsigned short* __restrict__ BT,
                                               OutT* __restrict__ C,
                                               int M, int N, int K) {
  __shared__ unsigned short As[128 * 32];
  __shared__ unsigned short Bs[128 * 32];
  const int nb = N >> 7;
  const int bm = blockIdx.x / nb, bn = blockIdx.x % nb;
  const int m0 = bm << 7, n0 = bn << 7;
  const int tid = threadIdx.x;
  const int lane = tid & 63, wave = tid >> 6;
  const int l15 = lane & 15, quad = lane >> 4;
  const int wm = (wave >> 1) << 6, wn = (wave & 1) << 6;

  floatx4 acc[4][4];
#pragma unroll
  for (int i = 0; i < 4; ++i)
#pragma unroll
    for (int j = 0; j < 4; ++j) acc[i][j] = (floatx4){0.f, 0.f, 0.f, 0.f};

  for (int k0 = 0; k0 < K; k0 += 32) {
    __syncthreads();
#pragma unroll
    for (int i = 0; i < 2; ++i) {
      int Lc = wave * 128 + i * 64 + lane;      // chunk in [0,512)
      int row = Lc >> 2;
      int c = (lane & 3) ^ ((row >> 1) & 3);
      async16(As + (size_t)Lc * 8, A + (size_t)(m0 + row) * K + k0 + c * 8);
      async16(Bs + (size_t)Lc * 8, BT + (size_t)(n0 + row) * K + k0 + c * 8);
    }
    __syncthreads();
    short8 af[4], bf[4];
#pragma unroll
    for (int mt = 0; mt < 4; ++mt) {
      int m = wm + mt * 16 + l15;
      af[mt] = *(const short8*)(&As[(m * 4 + (quad ^ ((m >> 1) & 3))) * 8]);
    }
#pragma unroll
    for (int nt = 0; nt < 4; ++nt) {
      int n = wn + nt * 16 + l15;
      bf[nt] = *(const short8*)(&Bs[(n * 4 + (quad ^ ((n >> 1) & 3))) * 8]);
    }
#pragma unroll
    for (int mt = 0; mt < 4; ++mt)
#pragma unroll
      for (int nt = 0; nt < 4; ++nt)
        acc[mt][nt] = __builtin_amdgcn_mfma_f32_16x16x32_bf16(af[mt], bf[nt], acc[mt][nt], 0, 0, 0);
  }
#pragma unroll
  for (int mt = 0; mt < 4; ++mt)
#pragma unroll
    for (int nt = 0; nt < 4; ++nt)
#pragma unroll
      for (int r = 0; r < 4; ++r) {
        int m = m0 + wm + mt * 16 + quad * 4 + r;
        int n = n0 + wn + nt * 16 + l15;
        float v = acc[mt][nt][r];
        if constexpr (sizeof(OutT) == 2)
          C[(size_t)m * N + n] = (OutT)f2bf(v);
        else
          C[(size_t)m * N + n] = (OutT)v;
      }
}

// ---------------------------------------------------------------------------
// RMS-norm + RoPE for q (heads 0..15, 1/sqrt(128) folded) and k (kv 0..3).
__global__ __launch_bounds__(256) void norm_rope(const unsigned short* __restrict__ qkv,
                                                 const float* __restrict__ qw,
                                                 const float* __restrict__ kw,
                                                 unsigned short* __restrict__ qT,
                                                 unsigned short* __restrict__ kT) {
  const int S = 2048;
  int wid = blockIdx.x * 4 + (threadIdx.x >> 6);
  int lane = threadIdx.x & 63;
  int slot = wid % 20;
  int bs = wid / 20;
  int s = bs & (S - 1), b = bs >> 11;
  const unsigned short* src;
  unsigned short* dst;
  const float* w;
  float scale;
  if (slot < 16) {
    src = qkv + (size_t)bs * 3072 + slot * 128;
    dst = qT + ((size_t)(b * 16 + slot) * S + s) * 128;
    w = qw; scale = 0.08838834764831845f;  // 1/sqrt(128)
  } else {
    int kvi = slot - 16;
    src = qkv + (size_t)bs * 3072 + 2048 + kvi * 128;
    dst = kT + ((size_t)(b * 4 + kvi) * S + s) * 128;
    w = kw; scale = 1.0f;
  }
  float x1 = bf2f(src[lane]), x2 = bf2f(src[lane + 64]);
  float ss = x1 * x1 + x2 * x2;
#pragma unroll
  for (int m = 1; m < 64; m <<= 1) ss += __shfl_xor(ss, m, 64);
  float rms = rsqrtf(ss * (1.0f / 128.0f) + 1e-6f);
  float y1 = x1 * rms * w[lane];
  float y2 = x2 * rms * w[lane + 64];
  float ang = (float)s * exp2f((float)lane * -0.2076205059304601f);
  float c = cosf(ang), sn = sinf(ang);
  float o1 = (y1 * c - y2 * sn) * scale;
  float o2 = (y2 * c + y1 * sn) * scale;
  dst[lane] = f2bf(o1);
  dst[lane + 64] = f2bf(o2);
}

// ---------------------------------------------------------------------------
// V transpose: qkv v-slice (B,S,KV,128) bf16 -> vT (B,KV,128,S) bf16. 64x64 tiles.
__global__ __launch_bounds__(256) void v_transpose(const unsigned short* __restrict__ qkv,
                                                   unsigned short* __restrict__ vT) {
  const int S = 2048;
  int bid = blockIdx.x;
  int dt = bid & 1, st = (bid >> 1) & 31, kv = (bid >> 6) & 3, b = bid >> 8;
  int s0 = st << 6, d0 = dt << 6;
  __shared__ unsigned short tile[64][65];
  int i = threadIdx.x >> 2, cc = (threadIdx.x & 3) << 4;
  union { uint4 v[2]; unsigned short u[16]; } buf;
  const uint4* g = (const uint4*)(qkv + ((size_t)(b * S) + s0 + i) * 3072 + 2560 + kv * 128 + d0 + cc);
  buf.v[0] = g[0]; buf.v[1] = g[1];
#pragma unroll
  for (int j = 0; j < 16; ++j) tile[i][cc + j] = buf.u[j];
  __syncthreads();
#pragma unroll
  for (int j = 0; j < 16; ++j) buf.u[j] = tile[cc + j][i];
  uint4* o = (uint4*)(vT + ((size_t)(b * 4 + kv) * 128 + d0 + i) * S + s0 + cc);
  o[0] = buf.v[0]; o[1] = buf.v[1];
}

// ---------------------------------------------------------------------------
// MFMA flash attention v2, non-causal. Block = (b,h,128 q-rows), 4 waves x 32 rows.
// Computes S^T (A=K, B=Q) so softmax reduce = 2 shuffles and P^T writes pack to b64
// in PV-A layout. K/V staged via global_load_lds with XOR swizzle (2-way banks).
// Q frags register-resident. Output ao (B,S,H,128) bf16.
__global__ __launch_bounds__(256, 2) void flash_attn(const unsigned short* __restrict__ qT,
                                                     const unsigned short* __restrict__ kT,
                                                     const unsigned short* __restrict__ vT,
                                                     unsigned short* __restrict__ ao) {
  const int S = 2048;
  int bid = blockIdx.x;
  int qt = bid & 15, h = (bid >> 4) & 15, b = bid >> 8;
  int kv = h >> 2;
  int tid = threadIdx.x;
  int lane = tid & 63, wave = tid >> 6;
  int l15 = lane & 15, quad = lane >> 4;

  __shared__ unsigned short Ks[64 * 128];     // 64 keys x 128 dh; 16 chunks/row, swizzled
  __shared__ unsigned short VTs[128 * 64];    // 128 d x 64 keys; 8 chunks/row, swizzled
  __shared__ unsigned short Ps[4 * 32 * 64];  // per-wave 32 qrows x 64 keys; swizzled
  unsigned short* Psw = Ps + wave * 2048;

  // Q fragments (B-operand of S^T: B[n=qrow][k=dh])
  short8 bq[2][4];
  const unsigned short* qbase = qT + ((size_t)(b * 16 + h) * S + qt * 128 + wave * 32) * 128;
#pragma unroll
  for (int nt = 0; nt < 2; ++nt)
#pragma unroll
    for (int kk = 0; kk < 4; ++kk)
      bq[nt][kk] = *(const short8*)(qbase + (size_t)(nt * 16 + l15) * 128 + kk * 32 + quad * 8);

  floatx4 O[2][8];
#pragma unroll
  for (int mt = 0; mt < 2; ++mt)
#pragma unroll
    for (int dt = 0; dt < 8; ++dt) O[mt][dt] = (floatx4){0.f, 0.f, 0.f, 0.f};
  float m_i[2] = {-1e30f, -1e30f};
  float l_i[2] = {0.f, 0.f};

  const size_t kbase = (size_t)(b * 4 + kv) * S * 128;
  const size_t vbase = (size_t)(b * 4 + kv) * 128 * S;

  for (int kt = 0; kt < 32; ++kt) {
    __syncthreads();
    // stage K tile (16 KB): 4 issues/wave; LDS slot L holds K[row=L>>4][8*((L&15)^(row&7))..]
#pragma unroll
    for (int i = 0; i < 4; ++i) {
      int Lc = (wave * 4 + i) * 64 + lane;
      int row = Lc >> 4;
      int cj = (lane & 15) ^ (row & 7);
      async16(Ks + (size_t)Lc * 8, kT + kbase + (size_t)(kt * 64 + row) * 128 + cj * 8);
    }
    // stage V^T tile (16 KB): slot L holds VT[d=L>>3][8*((L&7)^(d&7))..]
#pragma unroll
    for (int i = 0; i < 4; ++i) {
      int Lc = (wave * 4 + i) * 64 + lane;
      int d = Lc >> 3;
      int cj = (lane & 7) ^ (d & 7);
      async16(VTs + (size_t)Lc * 8, vT + vbase + (size_t)d * S + kt * 64 + cj * 8);
    }
    __syncthreads();

    // S^T = K * Q^T : C[m=key][n=qrow]
    floatx4 st[4][2];
#pragma unroll
    for (int a = 0; a < 4; ++a)
#pragma unroll
      for (int nt = 0; nt < 2; ++nt) st[a][nt] = (floatx4){0.f, 0.f, 0.f, 0.f};
#pragma unroll
    for (int kk = 0; kk < 4; ++kk)
#pragma unroll
      for (int a = 0; a < 4; ++a) {
        int m = a * 16 + l15;
        short8 ak = *(const short8*)(&Ks[(m * 16 + ((kk * 4 + quad) ^ (m & 7))) * 8]);
#pragma unroll
        for (int nt = 0; nt < 2; ++nt)
          st[a][nt] = __builtin_amdgcn_mfma_f32_16x16x32_bf16(ak, bq[nt][kk], st[a][nt], 0, 0, 0);
      }

    // online softmax per qrow (lane holds one qrow per nt: col=l15; keys on a,r,quad)
    float alpha[2];
#pragma unroll
    for (int nt = 0; nt < 2; ++nt) {
      float mx = -1e30f;
#pragma unroll
      for (int a = 0; a < 4; ++a)
#pragma unroll
        for (int r = 0; r < 4; ++r) mx = fmaxf(mx, st[a][nt][r]);
      mx = fmaxf(mx, __shfl_xor(mx, 16, 64));
      mx = fmaxf(mx, __shfl_xor(mx, 32, 64));
      float mn = fmaxf(m_i[nt], mx);
      alpha[nt] = exp2f((m_i[nt] - mn) * LOG2E);
      m_i[nt] = mn;
      float sum = 0.f;
#pragma unroll
      for (int a = 0; a < 4; ++a)
#pragma unroll
        for (int r = 0; r < 4; ++r) {
          float e = exp2f((st[a][nt][r] - mn) * LOG2E);
          st[a][nt][r] = e; sum += e;
        }
      sum += __shfl_xor(sum, 16, 64);
      sum += __shfl_xor(sum, 32, 64);
      l_i[nt] = l_i[nt] * alpha[nt] + sum;
    }
    // scale O by alpha (alpha for qrow mt*16+quad*4+r lives at lane quad*4+r)
#pragma unroll
    for (int mt = 0; mt < 2; ++mt)
#pragma unroll
      for (int r = 0; r < 4; ++r) {
        float av = __shfl(alpha[mt], quad * 4 + r, 64);
#pragma unroll
        for (int dt = 0; dt < 8; ++dt) O[mt][dt][r] *= av;
      }
    // write P^T -> Ps in PV-A layout: row m=qrow(nt*16+l15), keys a*16+quad*4+{0..3}
#pragma unroll
    for (int a = 0; a < 4; ++a)
#pragma unroll
      for (int nt = 0; nt < 2; ++nt) {
        ushort4v pk;
        pk.x = f2bf(st[a][nt][0]); pk.y = f2bf(st[a][nt][1]);
        pk.z = f2bf(st[a][nt][2]); pk.w = f2bf(st[a][nt][3]);
        int m = nt * 16 + l15;
        int c = (a * 2 + (quad >> 1)) ^ (m & 7);
        *(ushort4v*)(&Psw[(m * 8 + c) * 8 + (quad & 1) * 4]) = pk;
      }
    // PV: O[m=qrow][n=d] += P[m][key] * VT[n][key]
#pragma unroll
    for (int kk2 = 0; kk2 < 2; ++kk2) {
      short8 ap[2];
#pragma unroll
      for (int mt = 0; mt < 2; ++mt) {
        int m = mt * 16 + l15;
        ap[mt] = *(const short8*)(&Psw[(m * 8 + ((kk2 * 4 + quad) ^ (m & 7))) * 8]);
      }
#pragma unroll
      for (int dt = 0; dt < 8; ++dt) {
        int n = dt * 16 + l15;
        short8 bv = *(const short8*)(&VTs[(n * 8 + ((kk2 * 4 + quad) ^ (n & 7))) * 8]);
#pragma unroll
        for (int mt = 0; mt < 2; ++mt)
          O[mt][dt] = __builtin_amdgcn_mfma_f32_16x16x32_bf16(ap[mt], bv, O[mt][dt], 0, 0, 0);
      }
    }
  }

  float linv[2] = {1.f / l_i[0], 1.f / l_i[1]};
#pragma unroll
  for (int mt = 0; mt < 2; ++mt)
#pragma unroll
    for (int r = 0; r < 4; ++r) {
      float inv = __shfl(linv[mt], quad * 4 + r, 64);
      int s = qt * 128 + wave * 32 + mt * 16 + quad * 4 + r;
#pragma unroll
      for (int dt = 0; dt < 8; ++dt) {
        int d = dt * 16 + l15;
        ao[((size_t)(b * S + s) * 16 + h) * 128 + d] = f2bf(O[mt][dt][r] * inv);
      }
    }
}

// ---------------------------------------------------------------------------
extern "C" void kernel_launch(void* const* d_in, const int* in_sizes, int n_in,
                              void* d_out, int out_size, void* d_ws, size_t ws_size,
                              hipStream_t stream) {
  const float* x  = (const float*)d_in[0];
  const float* Wq = (const float*)d_in[1];
  const float* Wk = (const float*)d_in[2];
  const float* Wv = (const float*)d_in[3];
  const float* Wo = (const float*)d_in[4];
  const float* qw = (const float*)d_in[5];
  const float* kw = (const float*)d_in[6];
  float* out = (float*)d_out;

  unsigned short* p = (unsigned short*)d_ws;
  unsigned short* xbf   = p; p += (size_t)4096 * 2048;
  unsigned short* WTqkv = p; p += (size_t)3072 * 2048;
  unsigned short* WoT   = p; p += (size_t)2048 * 2048;
  unsigned short* qkv   = p; p += (size_t)4096 * 3072;
  unsigned short* qTb   = p; p += (size_t)2 * 16 * 2048 * 128;
  unsigned short* kTb   = p; p += (size_t)2 * 4 * 2048 * 128;
  unsigned short* vTb   = p; p += (size_t)2 * 4 * 2048 * 128;
  unsigned short* ao    = p; p += (size_t)4096 * 2048;

  cvt_f32_bf16<<<4096, 256, 0, stream>>>(x, xbf, 4096 * 2048);
  transpose_cvt<<<1024, 256, 0, stream>>>(Wq, WTqkv, 2048, 2048);
  transpose_cvt<<<256, 256, 0, stream>>>(Wk, WTqkv + (size_t)2048 * 2048, 2048, 512);
  transpose_cvt<<<256, 256, 0, stream>>>(Wv, WTqkv + (size_t)2048 * 2048 + (size_t)512 * 2048, 2048, 512);
  transpose_cvt<<<1024, 256, 0, stream>>>(Wo, WoT, 2048, 2048);

  gemm_nt<unsigned short><<<768, 256, 0, stream>>>(xbf, WTqkv, qkv, 4096, 3072, 2048);

  norm_rope<<<20480, 256, 0, stream>>>(qkv, qw, kw, qTb, kTb);
  v_transpose<<<512, 256, 0, stream>>>(qkv, vTb);

  flash_attn<<<512, 256, 0, stream>>>(qTb, kTb, vTb, ao);

  gemm_nt<float><<<512, 256, 0, stream>>>(ao, WoT, out, 4096, 2048, 2048);
}

// Round 4
// 348.271 us; speedup vs baseline: 1.3943x; 1.1051x over previous
//
#include <hip/hip_runtime.h>
#include <stdint.h>

#define LOG2E 1.4426950408889634f

typedef __attribute__((ext_vector_type(8))) short short8;
typedef __attribute__((ext_vector_type(4))) float floatx4;
typedef unsigned int u32;

__device__ __forceinline__ float bf2f(unsigned short h) {
  union { unsigned int u; float f; } v; v.u = ((unsigned int)h) << 16; return v.f;
}
__device__ __forceinline__ unsigned short f2bf(float f) {
  union { float f; unsigned int u; } v; v.f = f;
  unsigned int r = v.u + 0x7FFFu + ((v.u >> 16) & 1u);
  return (unsigned short)(r >> 16);
}
__device__ __forceinline__ u32 fbits(float f) {
  union { float f; u32 u; } v; v.f = f; return v.u;
}
// async global->LDS, 16B per lane. dst must be wave-contiguous (base + lane*16).
__device__ __forceinline__ void async16(void* lds, const void* g) {
  __builtin_amdgcn_global_load_lds((const __attribute__((address_space(1))) u32*)g,
                                   (__attribute__((address_space(3))) u32*)lds, 16, 0, 0);
}

// ---------------------------------------------------------------------------
// fp32 -> bf16 elementwise convert (8 elems/thread, vectorized)
__global__ __launch_bounds__(256) void cvt_f32_bf16(const float* __restrict__ src,
                                                    unsigned short* __restrict__ dst, int n) {
  int i = (blockIdx.x * 256 + threadIdx.x) * 8;
  if (i >= n) return;
  float4 a = ((const float4*)(src + i))[0];
  float4 b = ((const float4*)(src + i))[1];
  union { uint4 v; unsigned short u[8]; } o;
  o.u[0] = f2bf(a.x); o.u[1] = f2bf(a.y); o.u[2] = f2bf(a.z); o.u[3] = f2bf(a.w);
  o.u[4] = f2bf(b.x); o.u[5] = f2bf(b.y); o.u[6] = f2bf(b.z); o.u[7] = f2bf(b.w);
  *(uint4*)(dst + i) = o.v;
}

// ---------------------------------------------------------------------------
// Tiled transpose + fp32->bf16: src fp32 (R x C) -> dst bf16 (C x R). 64x64 tiles.
__global__ __launch_bounds__(256) void transpose_cvt(const float* __restrict__ src,
                                                     unsigned short* __restrict__ dst,
                                                     int R, int C) {
  __shared__ unsigned short tile[64][65];
  int tc = C >> 6;
  int br = blockIdx.x / tc, bc = blockIdx.x % tc;
  int r0 = br << 6, c0 = bc << 6;
  int i = threadIdx.x >> 2, cc = (threadIdx.x & 3) << 4;
  const float4* g = (const float4*)(src + (size_t)(r0 + i) * C + c0 + cc);
  float4 f0 = g[0], f1 = g[1], f2 = g[2], f3 = g[3];
  unsigned short u[16];
  u[0]=f2bf(f0.x); u[1]=f2bf(f0.y); u[2]=f2bf(f0.z); u[3]=f2bf(f0.w);
  u[4]=f2bf(f1.x); u[5]=f2bf(f1.y); u[6]=f2bf(f1.z); u[7]=f2bf(f1.w);
  u[8]=f2bf(f2.x); u[9]=f2bf(f2.y); u[10]=f2bf(f2.z); u[11]=f2bf(f2.w);
  u[12]=f2bf(f3.x); u[13]=f2bf(f3.y); u[14]=f2bf(f3.z); u[15]=f2bf(f3.w);
#pragma unroll
  for (int j = 0; j < 16; ++j) tile[i][cc + j] = u[j];
  __syncthreads();
  union { uint4 v[2]; unsigned short u[16]; } buf;
#pragma unroll
  for (int j = 0; j < 16; ++j) buf.u[j] = tile[cc + j][i];
  uint4* o = (uint4*)(dst + (size_t)(c0 + i) * R + r0 + cc);
  o[0] = buf.v[0]; o[1] = buf.v[1];
}

// ---------------------------------------------------------------------------
// NT GEMM: C(M,N) = A(M,K) * BT(N,K)^T, bf16 in, fp32 accum, OutT out.
// 128x128 tile, BK=32, global_load_lds(16B) staging with 2-bit XOR swizzle.
template <typename OutT>
__global__ __launch_bounds__(256) void gemm_nt(const unsigned short* __restrict__ A,
                                               const unsigned short* __restrict__ BT,
                                               OutT* __restrict__ C,
                                               int M, int N, int K) {
  __shared__ unsigned short As[128 * 32];
  __shared__ unsigned short Bs[128 * 32];
  const int nb = N >> 7;
  const int bm = blockIdx.x / nb, bn = blockIdx.x % nb;
  const int m0 = bm << 7, n0 = bn << 7;
  const int tid = threadIdx.x;
  const int lane = tid & 63, wave = tid >> 6;
  const int l15 = lane & 15, quad = lane >> 4;
  const int wm = (wave >> 1) << 6, wn = (wave & 1) << 6;

  floatx4 acc[4][4];
#pragma unroll
  for (int i = 0; i < 4; ++i)
#pragma unroll
    for (int j = 0; j < 4; ++j) acc[i][j] = (floatx4){0.f, 0.f, 0.f, 0.f};

  for (int k0 = 0; k0 < K; k0 += 32) {
    __syncthreads();
#pragma unroll
    for (int i = 0; i < 2; ++i) {
      int Lc = wave * 128 + i * 64 + lane;      // chunk in [0,512)
      int row = Lc >> 2;
      int c = (lane & 3) ^ ((row >> 1) & 3);
      async16(As + (size_t)Lc * 8, A + (size_t)(m0 + row) * K + k0 + c * 8);
      async16(Bs + (size_t)Lc * 8, BT + (size_t)(n0 + row) * K + k0 + c * 8);
    }
    __syncthreads();
    short8 af[4], bf[4];
#pragma unroll
    for (int mt = 0; mt < 4; ++mt) {
      int m = wm + mt * 16 + l15;
      af[mt] = *(const short8*)(&As[(m * 4 + (quad ^ ((m >> 1) & 3))) * 8]);
    }
#pragma unroll
    for (int nt = 0; nt < 4; ++nt) {
      int n = wn + nt * 16 + l15;
      bf[nt] = *(const short8*)(&Bs[(n * 4 + (quad ^ ((n >> 1) & 3))) * 8]);
    }
#pragma unroll
    for (int mt = 0; mt < 4; ++mt)
#pragma unroll
      for (int nt = 0; nt < 4; ++nt)
        acc[mt][nt] = __builtin_amdgcn_mfma_f32_16x16x32_bf16(af[mt], bf[nt], acc[mt][nt], 0, 0, 0);
  }
#pragma unroll
  for (int mt = 0; mt < 4; ++mt)
#pragma unroll
    for (int nt = 0; nt < 4; ++nt)
#pragma unroll
      for (int r = 0; r < 4; ++r) {
        int m = m0 + wm + mt * 16 + quad * 4 + r;
        int n = n0 + wn + nt * 16 + l15;
        float v = acc[mt][nt][r];
        if constexpr (sizeof(OutT) == 2)
          C[(size_t)m * N + n] = (OutT)f2bf(v);
        else
          C[(size_t)m * N + n] = (OutT)v;
      }
}

// ---------------------------------------------------------------------------
// RMS-norm + RoPE for q (heads 0..15) and k (kv 0..3).
// q gets 1/sqrt(128)*LOG2E folded in: flash then uses exp2(score) directly.
__global__ __launch_bounds__(256) void norm_rope(const unsigned short* __restrict__ qkv,
                                                 const float* __restrict__ qw,
                                                 const float* __restrict__ kw,
                                                 unsigned short* __restrict__ qT,
                                                 unsigned short* __restrict__ kT) {
  const int S = 2048;
  int wid = blockIdx.x * 4 + (threadIdx.x >> 6);
  int lane = threadIdx.x & 63;
  int slot = wid % 20;
  int bs = wid / 20;
  int s = bs & (S - 1), b = bs >> 11;
  const unsigned short* src;
  unsigned short* dst;
  const float* w;
  float scale;
  if (slot < 16) {
    src = qkv + (size_t)bs * 3072 + slot * 128;
    dst = qT + ((size_t)(b * 16 + slot) * S + s) * 128;
    w = qw; scale = 0.08838834764831845f * 1.4426950408889634f;  // 1/sqrt(128) * log2(e)
  } else {
    int kvi = slot - 16;
    src = qkv + (size_t)bs * 3072 + 2048 + kvi * 128;
    dst = kT + ((size_t)(b * 4 + kvi) * S + s) * 128;
    w = kw; scale = 1.0f;
  }
  float x1 = bf2f(src[lane]), x2 = bf2f(src[lane + 64]);
  float ss = x1 * x1 + x2 * x2;
#pragma unroll
  for (int m = 1; m < 64; m <<= 1) ss += __shfl_xor(ss, m, 64);
  float rms = rsqrtf(ss * (1.0f / 128.0f) + 1e-6f);
  float y1 = x1 * rms * w[lane];
  float y2 = x2 * rms * w[lane + 64];
  float ang = (float)s * exp2f((float)lane * -0.2076205059304601f);
  float c = cosf(ang), sn = sinf(ang);
  float o1 = (y1 * c - y2 * sn) * scale;
  float o2 = (y2 * c + y1 * sn) * scale;
  dst[lane] = f2bf(o1);
  dst[lane + 64] = f2bf(o2);
}

// ---------------------------------------------------------------------------
// V transpose: qkv v-slice (B,S,KV,128) bf16 -> vT (B,KV,128,S) bf16. 64x64 tiles.
__global__ __launch_bounds__(256) void v_transpose(const unsigned short* __restrict__ qkv,
                                                   unsigned short* __restrict__ vT) {
  const int S = 2048;
  int bid = blockIdx.x;
  int dt = bid & 1, st = (bid >> 1) & 31, kv = (bid >> 6) & 3, b = bid >> 8;
  int s0 = st << 6, d0 = dt << 6;
  __shared__ unsigned short tile[64][65];
  int i = threadIdx.x >> 2, cc = (threadIdx.x & 3) << 4;
  union { uint4 v[2]; unsigned short u[16]; } buf;
  const uint4* g = (const uint4*)(qkv + ((size_t)(b * S) + s0 + i) * 3072 + 2560 + kv * 128 + d0 + cc);
  buf.v[0] = g[0]; buf.v[1] = g[1];
#pragma unroll
  for (int j = 0; j < 16; ++j) tile[i][cc + j] = buf.u[j];
  __syncthreads();
#pragma unroll
  for (int j = 0; j < 16; ++j) buf.u[j] = tile[cc + j][i];
  uint4* o = (uint4*)(vT + ((size_t)(b * 4 + kv) * 128 + d0 + i) * S + s0 + cc);
  o[0] = buf.v[0]; o[1] = buf.v[1];
}

// ---------------------------------------------------------------------------
// MFMA flash attention v3, non-causal. Block = (b,h,128 q-rows), 4 waves x 32 rows.
// No-max softmax (scores bounded: |s|<=sqrt(128), LOG2E pre-folded into q, so
// P = exp2(S^T) directly; l accumulated per-lane, reduced once in epilogue).
// K/V double-buffered via global_load_lds prefetch; single barrier per kt.
__global__ __launch_bounds__(256, 2) void flash_attn(const unsigned short* __restrict__ qT,
                                                     const unsigned short* __restrict__ kT,
                                                     const unsigned short* __restrict__ vT,
                                                     unsigned short* __restrict__ ao) {
  const int S = 2048;
  int bid = blockIdx.x;
  int qt = bid & 15, h = (bid >> 4) & 15, b = bid >> 8;
  int kv = h >> 2;
  int tid = threadIdx.x;
  int lane = tid & 63, wave = tid >> 6;
  int l15 = lane & 15, quad = lane >> 4;

  __shared__ unsigned short Ks[2][64 * 128];   // keys x dh, 16 chunks/row, XOR swizzled
  __shared__ unsigned short VTs[2][128 * 64];  // d x keys, 8 chunks/row, XOR swizzled
  __shared__ unsigned short Ps[4][32 * 64];    // per-wave P in PV-A layout, swizzled
  unsigned short* Psw = Ps[wave];

  // Q fragments (B-operand of S^T: B[n=qrow][k=dh]), register-resident
  short8 bq[2][4];
  const unsigned short* qbase = qT + ((size_t)(b * 16 + h) * S + qt * 128 + wave * 32) * 128;
#pragma unroll
  for (int nt = 0; nt < 2; ++nt)
#pragma unroll
    for (int kk = 0; kk < 4; ++kk)
      bq[nt][kk] = *(const short8*)(qbase + (size_t)(nt * 16 + l15) * 128 + kk * 32 + quad * 8);

  floatx4 O[2][8];
#pragma unroll
  for (int mt = 0; mt < 2; ++mt)
#pragma unroll
    for (int dt = 0; dt < 8; ++dt) O[mt][dt] = (floatx4){0.f, 0.f, 0.f, 0.f};
  float l_acc[2] = {0.f, 0.f};

  const size_t kbase = (size_t)(b * 4 + kv) * S * 128;
  const size_t vbase = (size_t)(b * 4 + kv) * 128 * S;

  // prefetch tile 0 into buffer 0
#pragma unroll
  for (int i = 0; i < 4; ++i) {
    int Lc = (wave * 4 + i) * 64 + lane;
    int row = Lc >> 4, cjk = (lane & 15) ^ (row & 7);
    async16(Ks[0] + (size_t)Lc * 8, kT + kbase + (size_t)row * 128 + cjk * 8);
    int d = Lc >> 3, cjv = (lane & 7) ^ (d & 7);
    async16(VTs[0] + (size_t)Lc * 8, vT + vbase + (size_t)d * S + cjv * 8);
  }

  for (int kt = 0; kt < 32; ++kt) {
    int cur = kt & 1;
    __syncthreads();  // drains prefetch for tile kt; separates reads of buf cur^1 (kt-1) from restage
    if (kt + 1 < 32) {
#pragma unroll
      for (int i = 0; i < 4; ++i) {
        int Lc = (wave * 4 + i) * 64 + lane;
        int row = Lc >> 4, cjk = (lane & 15) ^ (row & 7);
        async16(Ks[cur ^ 1] + (size_t)Lc * 8,
                kT + kbase + (size_t)((kt + 1) * 64 + row) * 128 + cjk * 8);
        int d = Lc >> 3, cjv = (lane & 7) ^ (d & 7);
        async16(VTs[cur ^ 1] + (size_t)Lc * 8,
                vT + vbase + (size_t)d * S + (kt + 1) * 64 + cjv * 8);
      }
    }

    // S^T = K * Q^T : C[m=key][n=qrow]
    floatx4 st[4][2];
#pragma unroll
    for (int a = 0; a < 4; ++a)
#pragma unroll
      for (int nt = 0; nt < 2; ++nt) st[a][nt] = (floatx4){0.f, 0.f, 0.f, 0.f};
#pragma unroll
    for (int kk = 0; kk < 4; ++kk)
#pragma unroll
      for (int a = 0; a < 4; ++a) {
        int m = a * 16 + l15;
        short8 ak = *(const short8*)(&Ks[cur][(m * 16 + ((kk * 4 + quad) ^ (m & 7))) * 8]);
#pragma unroll
        for (int nt = 0; nt < 2; ++nt)
          st[a][nt] = __builtin_amdgcn_mfma_f32_16x16x32_bf16(ak, bq[nt][kk], st[a][nt], 0, 0, 0);
      }

    // P = exp2(S^T) (no max needed: |score*log2e| <= 16.4); pack to bf16 and
    // store into per-wave Ps in PV-A layout; accumulate per-lane l partials.
#pragma unroll
    for (int nt = 0; nt < 2; ++nt) {
      int m = nt * 16 + l15;
#pragma unroll
      for (int a = 0; a < 4; ++a) {
        float e0 = __builtin_amdgcn_exp2f(st[a][nt][0]);
        float e1 = __builtin_amdgcn_exp2f(st[a][nt][1]);
        float e2 = __builtin_amdgcn_exp2f(st[a][nt][2]);
        float e3 = __builtin_amdgcn_exp2f(st[a][nt][3]);
        l_acc[nt] += (e0 + e1) + (e2 + e3);
        // round-half-up bf16 pack: (bits+0x8000) then byte-perm pairs
        u32 p01 = __builtin_amdgcn_perm(fbits(e1) + 0x8000u, fbits(e0) + 0x8000u, 0x07060302u);
        u32 p23 = __builtin_amdgcn_perm(fbits(e3) + 0x8000u, fbits(e2) + 0x8000u, 0x07060302u);
        int c = (a * 2 + (quad >> 1)) ^ (m & 7);
        uint2 pk; pk.x = p01; pk.y = p23;
        *(uint2*)(&Psw[(m * 8 + c) * 8 + (quad & 1) * 4]) = pk;
      }
    }

    // PV: O[m=qrow][n=d] += P[m][key] * VT[n][key]
#pragma unroll
    for (int kk2 = 0; kk2 < 2; ++kk2) {
      short8 ap[2];
#pragma unroll
      for (int mt = 0; mt < 2; ++mt) {
        int m = mt * 16 + l15;
        ap[mt] = *(const short8*)(&Psw[(m * 8 + ((kk2 * 4 + quad) ^ (m & 7))) * 8]);
      }
#pragma unroll
      for (int dt = 0; dt < 8; ++dt) {
        int n = dt * 16 + l15;
        short8 bv = *(const short8*)(&VTs[cur][(n * 8 + ((kk2 * 4 + quad) ^ (n & 7))) * 8]);
#pragma unroll
        for (int mt = 0; mt < 2; ++mt)
          O[mt][dt] = __builtin_amdgcn_mfma_f32_16x16x32_bf16(ap[mt], bv, O[mt][dt], 0, 0, 0);
      }
    }
  }

  // epilogue: reduce l across quads (keys split over quad lanes), normalize, store
  float linv[2];
#pragma unroll
  for (int nt = 0; nt < 2; ++nt) {
    float l = l_acc[nt];
    l += __shfl_xor(l, 16, 64);
    l += __shfl_xor(l, 32, 64);
    linv[nt] = 1.f / l;
  }
#pragma unroll
  for (int mt = 0; mt < 2; ++mt)
#pragma unroll
    for (int r = 0; r < 4; ++r) {
      float inv = __shfl(linv[mt], quad * 4 + r, 64);
      int s = qt * 128 + wave * 32 + mt * 16 + quad * 4 + r;
#pragma unroll
      for (int dt = 0; dt < 8; ++dt) {
        int d = dt * 16 + l15;
        ao[((size_t)(b * S + s) * 16 + h) * 128 + d] = f2bf(O[mt][dt][r] * inv);
      }
    }
}

// ---------------------------------------------------------------------------
extern "C" void kernel_launch(void* const* d_in, const int* in_sizes, int n_in,
                              void* d_out, int out_size, void* d_ws, size_t ws_size,
                              hipStream_t stream) {
  const float* x  = (const float*)d_in[0];
  const float* Wq = (const float*)d_in[1];
  const float* Wk = (const float*)d_in[2];
  const float* Wv = (const float*)d_in[3];
  const float* Wo = (const float*)d_in[4];
  const float* qw = (const float*)d_in[5];
  const float* kw = (const float*)d_in[6];
  float* out = (float*)d_out;

  unsigned short* p = (unsigned short*)d_ws;
  unsigned short* xbf   = p; p += (size_t)4096 * 2048;
  unsigned short* WTqkv = p; p += (size_t)3072 * 2048;
  unsigned short* WoT   = p; p += (size_t)2048 * 2048;
  unsigned short* qkv   = p; p += (size_t)4096 * 3072;
  unsigned short* qTb   = p; p += (size_t)2 * 16 * 2048 * 128;
  unsigned short* kTb   = p; p += (size_t)2 * 4 * 2048 * 128;
  unsigned short* vTb   = p; p += (size_t)2 * 4 * 2048 * 128;
  unsigned short* ao    = p; p += (size_t)4096 * 2048;

  cvt_f32_bf16<<<4096, 256, 0, stream>>>(x, xbf, 4096 * 2048);
  transpose_cvt<<<1024, 256, 0, stream>>>(Wq, WTqkv, 2048, 2048);
  transpose_cvt<<<256, 256, 0, stream>>>(Wk, WTqkv + (size_t)2048 * 2048, 2048, 512);
  transpose_cvt<<<256, 256, 0, stream>>>(Wv, WTqkv + (size_t)2048 * 2048 + (size_t)512 * 2048, 2048, 512);
  transpose_cvt<<<1024, 256, 0, stream>>>(Wo, WoT, 2048, 2048);

  gemm_nt<unsigned short><<<768, 256, 0, stream>>>(xbf, WTqkv, qkv, 4096, 3072, 2048);

  norm_rope<<<20480, 256, 0, stream>>>(qkv, qw, kw, qTb, kTb);
  v_transpose<<<512, 256, 0, stream>>>(qkv, vTb);

  flash_attn<<<512, 256, 0, stream>>>(qTb, kTb, vTb, ao);

  gemm_nt<float><<<512, 256, 0, stream>>>(ao, WoT, out, 4096, 2048, 2048);
}

// Round 5
// 325.921 us; speedup vs baseline: 1.4899x; 1.0686x over previous
//
#include <hip/hip_runtime.h>
#include <stdint.h>

#define LOG2E 1.4426950408889634f

typedef __attribute__((ext_vector_type(8))) short short8;
typedef __attribute__((ext_vector_type(4))) float floatx4;
typedef unsigned int u32;

__device__ __forceinline__ float bf2f(unsigned short h) {
  union { unsigned int u; float f; } v; v.u = ((unsigned int)h) << 16; return v.f;
}
__device__ __forceinline__ unsigned short f2bf(float f) {
  union { float f; unsigned int u; } v; v.f = f;
  unsigned int r = v.u + 0x7FFFu + ((v.u >> 16) & 1u);
  return (unsigned short)(r >> 16);
}
__device__ __forceinline__ u32 fbits(float f) {
  union { float f; u32 u; } v; v.f = f; return v.u;
}
// async global->LDS, 16B per lane. dst must be wave-contiguous (base + lane*16).
__device__ __forceinline__ void async16(void* lds, const void* g) {
  __builtin_amdgcn_global_load_lds((const __attribute__((address_space(1))) u32*)g,
                                   (__attribute__((address_space(3))) u32*)lds, 16, 0, 0);
}

// ---------------------------------------------------------------------------
// fp32 -> bf16 elementwise convert (8 elems/thread, vectorized)
__global__ __launch_bounds__(256) void cvt_f32_bf16(const float* __restrict__ src,
                                                    unsigned short* __restrict__ dst, int n) {
  int i = (blockIdx.x * 256 + threadIdx.x) * 8;
  if (i >= n) return;
  float4 a = ((const float4*)(src + i))[0];
  float4 b = ((const float4*)(src + i))[1];
  union { uint4 v; unsigned short u[8]; } o;
  o.u[0] = f2bf(a.x); o.u[1] = f2bf(a.y); o.u[2] = f2bf(a.z); o.u[3] = f2bf(a.w);
  o.u[4] = f2bf(b.x); o.u[5] = f2bf(b.y); o.u[6] = f2bf(b.z); o.u[7] = f2bf(b.w);
  *(uint4*)(dst + i) = o.v;
}

// ---------------------------------------------------------------------------
// All 4 weight transposes (+fp32->bf16) in one launch. 64x64 tiles.
// blocks [0,1024): Wq->WTqkv ; [1024,1280): Wk ; [1280,1536): Wv ; [1536,2560): Wo->WoT
__global__ __launch_bounds__(256) void transpose_cvt4(const float* __restrict__ Wq,
                                                      const float* __restrict__ Wk,
                                                      const float* __restrict__ Wv,
                                                      const float* __restrict__ Wo,
                                                      unsigned short* __restrict__ WTqkv,
                                                      unsigned short* __restrict__ WoT) {
  const int R = 2048;
  int bid = blockIdx.x;
  const float* src; unsigned short* dst; int C;
  if (bid < 1024) { src = Wq; dst = WTqkv; C = 2048; }
  else if (bid < 1280) { src = Wk; dst = WTqkv + (size_t)2048 * 2048; C = 512; bid -= 1024; }
  else if (bid < 1536) { src = Wv; dst = WTqkv + (size_t)2048 * 2048 + (size_t)512 * 2048; C = 512; bid -= 1280; }
  else { src = Wo; dst = WoT; C = 2048; bid -= 1536; }

  __shared__ unsigned short tile[64][65];
  int tc = C >> 6;
  int br = bid / tc, bc = bid % tc;
  int r0 = br << 6, c0 = bc << 6;
  int i = threadIdx.x >> 2, cc = (threadIdx.x & 3) << 4;
  const float4* g = (const float4*)(src + (size_t)(r0 + i) * C + c0 + cc);
  float4 f0 = g[0], f1 = g[1], f2 = g[2], f3 = g[3];
  unsigned short u[16];
  u[0]=f2bf(f0.x); u[1]=f2bf(f0.y); u[2]=f2bf(f0.z); u[3]=f2bf(f0.w);
  u[4]=f2bf(f1.x); u[5]=f2bf(f1.y); u[6]=f2bf(f1.z); u[7]=f2bf(f1.w);
  u[8]=f2bf(f2.x); u[9]=f2bf(f2.y); u[10]=f2bf(f2.z); u[11]=f2bf(f2.w);
  u[12]=f2bf(f3.x); u[13]=f2bf(f3.y); u[14]=f2bf(f3.z); u[15]=f2bf(f3.w);
#pragma unroll
  for (int j = 0; j < 16; ++j) tile[i][cc + j] = u[j];
  __syncthreads();
  union { uint4 v[2]; unsigned short u[16]; } buf;
#pragma unroll
  for (int j = 0; j < 16; ++j) buf.u[j] = tile[cc + j][i];
  uint4* o = (uint4*)(dst + (size_t)(c0 + i) * R + r0 + cc);
  o[0] = buf.v[0]; o[1] = buf.v[1];
}

// ---------------------------------------------------------------------------
// NT GEMM: C(M,N) = A(M,K) * BT(N,K)^T, bf16 in, fp32 accum, OutT out.
// 128x128 tile, BK=32, double-buffered global_load_lds(16B) staging with XOR
// swizzle; single barrier per K-iter (prefetch kt+1 covers its latency under
// the 16-MFMA compute phase of kt).
template <typename OutT>
__global__ __launch_bounds__(256) void gemm_nt(const unsigned short* __restrict__ A,
                                               const unsigned short* __restrict__ BT,
                                               OutT* __restrict__ C,
                                               int M, int N, int K) {
  __shared__ unsigned short As[2][128 * 32];
  __shared__ unsigned short Bs[2][128 * 32];
  const int nb = N >> 7;
  const int bm = blockIdx.x / nb, bn = blockIdx.x % nb;
  const int m0 = bm << 7, n0 = bn << 7;
  const int tid = threadIdx.x;
  const int lane = tid & 63, wave = tid >> 6;
  const int l15 = lane & 15, quad = lane >> 4;
  const int wm = (wave >> 1) << 6, wn = (wave & 1) << 6;

  floatx4 acc[4][4];
#pragma unroll
  for (int i = 0; i < 4; ++i)
#pragma unroll
    for (int j = 0; j < 4; ++j) acc[i][j] = (floatx4){0.f, 0.f, 0.f, 0.f};

  // staging: chunk Lc in [0,512): row = Lc>>2, col-chunk swizzled by row
  const int Lc0 = wave * 128 + lane;          // first of 2 chunk slots (stride 64)
#pragma unroll 1
  for (int pre = 0; pre < 1; ++pre) {         // prefetch tile 0 -> buf 0
#pragma unroll
    for (int i = 0; i < 2; ++i) {
      int Lc = Lc0 + i * 64;
      int row = Lc >> 2;
      int c = (lane & 3) ^ ((row >> 1) & 3);
      async16(As[0] + (size_t)Lc * 8, A + (size_t)(m0 + row) * K + c * 8);
      async16(Bs[0] + (size_t)Lc * 8, BT + (size_t)(n0 + row) * K + c * 8);
    }
  }

  const int nk = K >> 5;
  for (int it = 0; it < nk; ++it) {
    const int cur = it & 1;
    __syncthreads();   // drains prefetch of tile it; fences reads of buf cur^1 (it-1)
    if (it + 1 < nk) {
      int k1 = (it + 1) << 5;
#pragma unroll
      for (int i = 0; i < 2; ++i) {
        int Lc = Lc0 + i * 64;
        int row = Lc >> 2;
        int c = (lane & 3) ^ ((row >> 1) & 3);
        async16(As[cur ^ 1] + (size_t)Lc * 8, A + (size_t)(m0 + row) * K + k1 + c * 8);
        async16(Bs[cur ^ 1] + (size_t)Lc * 8, BT + (size_t)(n0 + row) * K + k1 + c * 8);
      }
    }
    short8 af[4], bf[4];
#pragma unroll
    for (int mt = 0; mt < 4; ++mt) {
      int m = wm + mt * 16 + l15;
      af[mt] = *(const short8*)(&As[cur][(m * 4 + (quad ^ ((m >> 1) & 3))) * 8]);
    }
#pragma unroll
    for (int nt = 0; nt < 4; ++nt) {
      int n = wn + nt * 16 + l15;
      bf[nt] = *(const short8*)(&Bs[cur][(n * 4 + (quad ^ ((n >> 1) & 3))) * 8]);
    }
#pragma unroll
    for (int mt = 0; mt < 4; ++mt)
#pragma unroll
      for (int nt = 0; nt < 4; ++nt)
        acc[mt][nt] = __builtin_amdgcn_mfma_f32_16x16x32_bf16(af[mt], bf[nt], acc[mt][nt], 0, 0, 0);
  }
#pragma unroll
  for (int mt = 0; mt < 4; ++mt)
#pragma unroll
    for (int nt = 0; nt < 4; ++nt)
#pragma unroll
      for (int r = 0; r < 4; ++r) {
        int m = m0 + wm + mt * 16 + quad * 4 + r;
        int n = n0 + wn + nt * 16 + l15;
        float v = acc[mt][nt][r];
        if constexpr (sizeof(OutT) == 2)
          C[(size_t)m * N + n] = (OutT)f2bf(v);
        else
          C[(size_t)m * N + n] = (OutT)v;
      }
}

// ---------------------------------------------------------------------------
// RMS-norm + RoPE for q (heads 0..15) and k (kv 0..3).
// q gets 1/sqrt(128)*LOG2E folded in: flash then uses exp2(score) directly.
__global__ __launch_bounds__(256) void norm_rope(const unsigned short* __restrict__ qkv,
                                                 const float* __restrict__ qw,
                                                 const float* __restrict__ kw,
                                                 unsigned short* __restrict__ qT,
                                                 unsigned short* __restrict__ kT) {
  const int S = 2048;
  int wid = blockIdx.x * 4 + (threadIdx.x >> 6);
  int lane = threadIdx.x & 63;
  int slot = wid % 20;
  int bs = wid / 20;
  int s = bs & (S - 1), b = bs >> 11;
  const unsigned short* src;
  unsigned short* dst;
  const float* w;
  float scale;
  if (slot < 16) {
    src = qkv + (size_t)bs * 3072 + slot * 128;
    dst = qT + ((size_t)(b * 16 + slot) * S + s) * 128;
    w = qw; scale = 0.08838834764831845f * 1.4426950408889634f;  // 1/sqrt(128) * log2(e)
  } else {
    int kvi = slot - 16;
    src = qkv + (size_t)bs * 3072 + 2048 + kvi * 128;
    dst = kT + ((size_t)(b * 4 + kvi) * S + s) * 128;
    w = kw; scale = 1.0f;
  }
  float x1 = bf2f(src[lane]), x2 = bf2f(src[lane + 64]);
  float ss = x1 * x1 + x2 * x2;
#pragma unroll
  for (int m = 1; m < 64; m <<= 1) ss += __shfl_xor(ss, m, 64);
  float rms = rsqrtf(ss * (1.0f / 128.0f) + 1e-6f);
  float y1 = x1 * rms * w[lane];
  float y2 = x2 * rms * w[lane + 64];
  float ang = (float)s * exp2f((float)lane * -0.2076205059304601f);
  float c = cosf(ang), sn = sinf(ang);
  float o1 = (y1 * c - y2 * sn) * scale;
  float o2 = (y2 * c + y1 * sn) * scale;
  dst[lane] = f2bf(o1);
  dst[lane + 64] = f2bf(o2);
}

// ---------------------------------------------------------------------------
// V transpose: qkv v-slice (B,S,KV,128) bf16 -> vT (B,KV,128,S) bf16. 64x64 tiles.
__global__ __launch_bounds__(256) void v_transpose(const unsigned short* __restrict__ qkv,
                                                   unsigned short* __restrict__ vT) {
  const int S = 2048;
  int bid = blockIdx.x;
  int dt = bid & 1, st = (bid >> 1) & 31, kv = (bid >> 6) & 3, b = bid >> 8;
  int s0 = st << 6, d0 = dt << 6;
  __shared__ unsigned short tile[64][65];
  int i = threadIdx.x >> 2, cc = (threadIdx.x & 3) << 4;
  union { uint4 v[2]; unsigned short u[16]; } buf;
  const uint4* g = (const uint4*)(qkv + ((size_t)(b * S) + s0 + i) * 3072 + 2560 + kv * 128 + d0 + cc);
  buf.v[0] = g[0]; buf.v[1] = g[1];
#pragma unroll
  for (int j = 0; j < 16; ++j) tile[i][cc + j] = buf.u[j];
  __syncthreads();
#pragma unroll
  for (int j = 0; j < 16; ++j) buf.u[j] = tile[cc + j][i];
  uint4* o = (uint4*)(vT + ((size_t)(b * 4 + kv) * 128 + d0 + i) * S + s0 + cc);
  o[0] = buf.v[0]; o[1] = buf.v[1];
}

// ---------------------------------------------------------------------------
// MFMA flash attention v3, non-causal. Block = (b,h,128 q-rows), 4 waves x 32 rows.
// No-max softmax (scores bounded: |s|<=sqrt(128), LOG2E pre-folded into q).
// K/V double-buffered via global_load_lds prefetch; single barrier per kt.
__global__ __launch_bounds__(256, 2) void flash_attn(const unsigned short* __restrict__ qT,
                                                     const unsigned short* __restrict__ kT,
                                                     const unsigned short* __restrict__ vT,
                                                     unsigned short* __restrict__ ao) {
  const int S = 2048;
  int bid = blockIdx.x;
  int qt = bid & 15, h = (bid >> 4) & 15, b = bid >> 8;
  int kv = h >> 2;
  int tid = threadIdx.x;
  int lane = tid & 63, wave = tid >> 6;
  int l15 = lane & 15, quad = lane >> 4;

  __shared__ unsigned short Ks[2][64 * 128];   // keys x dh, 16 chunks/row, XOR swizzled
  __shared__ unsigned short VTs[2][128 * 64];  // d x keys, 8 chunks/row, XOR swizzled
  __shared__ unsigned short Ps[4][32 * 64];    // per-wave P in PV-A layout, swizzled
  unsigned short* Psw = Ps[wave];

  // Q fragments (B-operand of S^T: B[n=qrow][k=dh]), register-resident
  short8 bq[2][4];
  const unsigned short* qbase = qT + ((size_t)(b * 16 + h) * S + qt * 128 + wave * 32) * 128;
#pragma unroll
  for (int nt = 0; nt < 2; ++nt)
#pragma unroll
    for (int kk = 0; kk < 4; ++kk)
      bq[nt][kk] = *(const short8*)(qbase + (size_t)(nt * 16 + l15) * 128 + kk * 32 + quad * 8);

  floatx4 O[2][8];
#pragma unroll
  for (int mt = 0; mt < 2; ++mt)
#pragma unroll
    for (int dt = 0; dt < 8; ++dt) O[mt][dt] = (floatx4){0.f, 0.f, 0.f, 0.f};
  float l_acc[2] = {0.f, 0.f};

  const size_t kbase = (size_t)(b * 4 + kv) * S * 128;
  const size_t vbase = (size_t)(b * 4 + kv) * 128 * S;

  // prefetch tile 0 into buffer 0
#pragma unroll
  for (int i = 0; i < 4; ++i) {
    int Lc = (wave * 4 + i) * 64 + lane;
    int row = Lc >> 4, cjk = (lane & 15) ^ (row & 7);
    async16(Ks[0] + (size_t)Lc * 8, kT + kbase + (size_t)row * 128 + cjk * 8);
    int d = Lc >> 3, cjv = (lane & 7) ^ (d & 7);
    async16(VTs[0] + (size_t)Lc * 8, vT + vbase + (size_t)d * S + cjv * 8);
  }

  for (int kt = 0; kt < 32; ++kt) {
    int cur = kt & 1;
    __syncthreads();  // drains prefetch for tile kt; fences reads of buf cur^1 (kt-1)
    if (kt + 1 < 32) {
#pragma unroll
      for (int i = 0; i < 4; ++i) {
        int Lc = (wave * 4 + i) * 64 + lane;
        int row = Lc >> 4, cjk = (lane & 15) ^ (row & 7);
        async16(Ks[cur ^ 1] + (size_t)Lc * 8,
                kT + kbase + (size_t)((kt + 1) * 64 + row) * 128 + cjk * 8);
        int d = Lc >> 3, cjv = (lane & 7) ^ (d & 7);
        async16(VTs[cur ^ 1] + (size_t)Lc * 8,
                vT + vbase + (size_t)d * S + (kt + 1) * 64 + cjv * 8);
      }
    }

    // S^T = K * Q^T : C[m=key][n=qrow]
    floatx4 st[4][2];
#pragma unroll
    for (int a = 0; a < 4; ++a)
#pragma unroll
      for (int nt = 0; nt < 2; ++nt) st[a][nt] = (floatx4){0.f, 0.f, 0.f, 0.f};
#pragma unroll
    for (int kk = 0; kk < 4; ++kk)
#pragma unroll
      for (int a = 0; a < 4; ++a) {
        int m = a * 16 + l15;
        short8 ak = *(const short8*)(&Ks[cur][(m * 16 + ((kk * 4 + quad) ^ (m & 7))) * 8]);
#pragma unroll
        for (int nt = 0; nt < 2; ++nt)
          st[a][nt] = __builtin_amdgcn_mfma_f32_16x16x32_bf16(ak, bq[nt][kk], st[a][nt], 0, 0, 0);
      }

    // P = exp2(S^T); pack to bf16 into per-wave Ps (PV-A layout); l partials per lane.
#pragma unroll
    for (int nt = 0; nt < 2; ++nt) {
      int m = nt * 16 + l15;
#pragma unroll
      for (int a = 0; a < 4; ++a) {
        float e0 = __builtin_amdgcn_exp2f(st[a][nt][0]);
        float e1 = __builtin_amdgcn_exp2f(st[a][nt][1]);
        float e2 = __builtin_amdgcn_exp2f(st[a][nt][2]);
        float e3 = __builtin_amdgcn_exp2f(st[a][nt][3]);
        l_acc[nt] += (e0 + e1) + (e2 + e3);
        u32 p01 = __builtin_amdgcn_perm(fbits(e1) + 0x8000u, fbits(e0) + 0x8000u, 0x07060302u);
        u32 p23 = __builtin_amdgcn_perm(fbits(e3) + 0x8000u, fbits(e2) + 0x8000u, 0x07060302u);
        int c = (a * 2 + (quad >> 1)) ^ (m & 7);
        uint2 pk; pk.x = p01; pk.y = p23;
        *(uint2*)(&Psw[(m * 8 + c) * 8 + (quad & 1) * 4]) = pk;
      }
    }

    // PV: O[m=qrow][n=d] += P[m][key] * VT[n][key]
#pragma unroll
    for (int kk2 = 0; kk2 < 2; ++kk2) {
      short8 ap[2];
#pragma unroll
      for (int mt = 0; mt < 2; ++mt) {
        int m = mt * 16 + l15;
        ap[mt] = *(const short8*)(&Psw[(m * 8 + ((kk2 * 4 + quad) ^ (m & 7))) * 8]);
      }
#pragma unroll
      for (int dt = 0; dt < 8; ++dt) {
        int n = dt * 16 + l15;
        short8 bv = *(const short8*)(&VTs[cur][(n * 8 + ((kk2 * 4 + quad) ^ (n & 7))) * 8]);
#pragma unroll
        for (int mt = 0; mt < 2; ++mt)
          O[mt][dt] = __builtin_amdgcn_mfma_f32_16x16x32_bf16(ap[mt], bv, O[mt][dt], 0, 0, 0);
      }
    }
  }

  // epilogue: reduce l across quads, normalize, store
  float linv[2];
#pragma unroll
  for (int nt = 0; nt < 2; ++nt) {
    float l = l_acc[nt];
    l += __shfl_xor(l, 16, 64);
    l += __shfl_xor(l, 32, 64);
    linv[nt] = 1.f / l;
  }
#pragma unroll
  for (int mt = 0; mt < 2; ++mt)
#pragma unroll
    for (int r = 0; r < 4; ++r) {
      float inv = __shfl(linv[mt], quad * 4 + r, 64);
      int s = qt * 128 + wave * 32 + mt * 16 + quad * 4 + r;
#pragma unroll
      for (int dt = 0; dt < 8; ++dt) {
        int d = dt * 16 + l15;
        ao[((size_t)(b * S + s) * 16 + h) * 128 + d] = f2bf(O[mt][dt][r] * inv);
      }
    }
}

// ---------------------------------------------------------------------------
extern "C" void kernel_launch(void* const* d_in, const int* in_sizes, int n_in,
                              void* d_out, int out_size, void* d_ws, size_t ws_size,
                              hipStream_t stream) {
  const float* x  = (const float*)d_in[0];
  const float* Wq = (const float*)d_in[1];
  const float* Wk = (const float*)d_in[2];
  const float* Wv = (const float*)d_in[3];
  const float* Wo = (const float*)d_in[4];
  const float* qw = (const float*)d_in[5];
  const float* kw = (const float*)d_in[6];
  float* out = (float*)d_out;

  unsigned short* p = (unsigned short*)d_ws;
  unsigned short* xbf   = p; p += (size_t)4096 * 2048;
  unsigned short* WTqkv = p; p += (size_t)3072 * 2048;
  unsigned short* WoT   = p; p += (size_t)2048 * 2048;
  unsigned short* qkv   = p; p += (size_t)4096 * 3072;
  unsigned short* qTb   = p; p += (size_t)2 * 16 * 2048 * 128;
  unsigned short* kTb   = p; p += (size_t)2 * 4 * 2048 * 128;
  unsigned short* vTb   = p; p += (size_t)2 * 4 * 2048 * 128;
  unsigned short* ao    = p; p += (size_t)4096 * 2048;

  cvt_f32_bf16<<<4096, 256, 0, stream>>>(x, xbf, 4096 * 2048);
  transpose_cvt4<<<2560, 256, 0, stream>>>(Wq, Wk, Wv, Wo, WTqkv, WoT);

  gemm_nt<unsigned short><<<768, 256, 0, stream>>>(xbf, WTqkv, qkv, 4096, 3072, 2048);

  norm_rope<<<20480, 256, 0, stream>>>(qkv, qw, kw, qTb, kTb);
  v_transpose<<<512, 256, 0, stream>>>(qkv, vTb);

  flash_attn<<<512, 256, 0, stream>>>(qTb, kTb, vTb, ao);

  gemm_nt<float><<<512, 256, 0, stream>>>(ao, WoT, out, 4096, 2048, 2048);
}